// Round 12
// baseline (1281.460 us; speedup 1.0000x reference)
//
#include <hip/hip_runtime.h>
#include <hip/hip_bf16.h>
#include <math.h>

// Problem constants (from reference)
constexpr int N_NODES = 50000;
constexpr int N_EDGES = 400000;
constexpr int F_IN    = 128;
constexpr int E_DIM   = 16;
constexpr int NH      = 4;    // heads
constexpr int CH      = 64;   // channels/head
constexpr int HC      = 256;  // NH*CH
constexpr int NG      = 64;   // graphs
constexpr int NOUT    = 10;

// NOTE ON NUMERICS: the final per-graph sort is bit-sensitive (one marginal
// score pair flips at ~1e-7 perturbations of `add`). The f64 chain below is
// the exact chain of the round-2 PASSING run. EMPIRICAL RULES:
//  - (R3, R6, R10 failures) any restructure that changes the FROZEN GEMM FMA
//    block's statements OR causes the compiler to clone/specialize it (e.g.
//    runtime-indexed LDS ping-pong -> loop unroll by 2 -> per-copy fma/mul+add
//    contraction choices) flips output bits.
//  - (R7, R8, R9, R11 passes) load/store-path changes OUTSIDE the frozen
//    block (alignment, padding, load widths, register prefetch, staging
//    remaps, load batching preserving f64 add order, dead-store elimination)
//    are bit-safe.

// ---------------------------------------------------------------------------
// integer in-degree per destination
__global__ void k_deg(const int* __restrict__ dst, int* __restrict__ deg) {
    int e = blockIdx.x * blockDim.x + threadIdx.x;
    if (e >= N_EDGES) return;
    atomicAdd(&deg[dst[e]], 1);
}

// 3-phase exclusive scan of deg -> row_start (integer-exact)
__global__ void k_scan1(const int* __restrict__ deg, int* __restrict__ row_start,
                        int* __restrict__ bsum) {
    __shared__ int sh[1024];
    int i = blockIdx.x * 1024 + threadIdx.x;
    int v = (i < N_NODES) ? deg[i] : 0;
    sh[threadIdx.x] = v;
    __syncthreads();
    for (int off = 1; off < 1024; off <<= 1) {
        int t = (threadIdx.x >= off) ? sh[threadIdx.x - off] : 0;
        __syncthreads();
        sh[threadIdx.x] += t;
        __syncthreads();
    }
    if (i < N_NODES) row_start[i + 1] = sh[threadIdx.x];   // local inclusive
    if (threadIdx.x == 1023) bsum[blockIdx.x] = sh[1023];
}
__global__ void k_scan2(int* __restrict__ bsum, int nb) {
    if (threadIdx.x == 0) {
        int s = 0;
        for (int b = 0; b < nb; b++) { int t = bsum[b]; bsum[b] = s; s += t; }
    }
}
__global__ void k_scan3(int* __restrict__ row_start, const int* __restrict__ bsum) {
    int i = blockIdx.x * blockDim.x + threadIdx.x;
    if (i == 0) row_start[0] = 0;
    if (i < N_NODES) row_start[i + 1] += bsum[i >> 10];
}

// counting-sort scatter of edge ids into CSR (by dst); racy fill order,
// k_sortrows restores deterministic ascending edge order afterwards.
__global__ void k_scatter(const int* __restrict__ dst, const int* __restrict__ row_start,
                          int* __restrict__ fill, int* __restrict__ csr_eid) {
    int e = blockIdx.x * blockDim.x + threadIdx.x;
    if (e >= N_EDGES) return;
    int d = dst[e];
    int pos = row_start[d] + atomicAdd(&fill[d], 1);
    csr_eid[pos] = e;
}

// insertion-sort each CSR row ascending (deg ~ Poisson(8))
__global__ void k_sortrows(const int* __restrict__ row_start, int* __restrict__ csr_eid) {
    int n = blockIdx.x * blockDim.x + threadIdx.x;
    if (n >= N_NODES) return;
    int rs = row_start[n], re = row_start[n + 1];
    for (int i = rs + 1; i < re; i++) {
        int key = csr_eid[i];
        int j = i - 1;
        while (j >= rs && csr_eid[j] > key) { csr_eid[j + 1] = csr_eid[j]; j--; }
        csr_eid[j + 1] = key;
    }
}

// pre-gather source node ids at (sorted) CSR positions
__global__ void k_gather_src(const int* __restrict__ csr_eid, const int* __restrict__ src,
                             int* __restrict__ csr_src) {
    int i = blockIdx.x * blockDim.x + threadIdx.x;
    if (i >= N_EDGES) return;
    csr_src[i] = src[csr_eid[i]];
}

// deterministic mean edge_attr per destination (ascending edge order, f64)
__global__ void k_mean_csr(const float* __restrict__ ea, const int* __restrict__ row_start,
                           const int* __restrict__ csr_eid, float* __restrict__ mean_ea) {
    int n = blockIdx.x * blockDim.x + threadIdx.x;
    if (n >= N_NODES) return;
    int rs = row_start[n], re = row_start[n + 1];
    double acc[E_DIM];
#pragma unroll
    for (int d = 0; d < E_DIM; d++) acc[d] = 0.0;
    for (int i = rs; i < re; i++) {
        const float* row = ea + (size_t)csr_eid[i] * E_DIM;
#pragma unroll
        for (int d = 0; d < E_DIM; d++) acc[d] += (double)row[d];
    }
    double dg = (double)(re - rs);
    if (dg < 1.0) dg = 1.0;
    float* orow = mean_ea + (size_t)n * E_DIM;
#pragma unroll
    for (int d = 0; d < E_DIM; d++) orow[d] = (float)(acc[d] / dg);
}

// v[l][h][d] = sum_c We_l[d][h*64+c] * ae_l[h][c]  (edge-logit projection, 3 layers)
__global__ void k_v(const float* __restrict__ we1, const float* __restrict__ ae1,
                    const float* __restrict__ we2, const float* __restrict__ ae2,
                    const float* __restrict__ we3, const float* __restrict__ ae3,
                    float* __restrict__ v) {
    int t = threadIdx.x;            // 0..191
    if (t >= 3 * NH * E_DIM) return;
    int l = t / (NH * E_DIM);
    int rem = t % (NH * E_DIM);
    int h = rem / E_DIM, d = rem % E_DIM;
    const float* We = (l == 0) ? we1 : (l == 1) ? we2 : we3;
    const float* ae = (l == 0) ? ae1 : (l == 1) ? ae2 : ae3;
    double s = 0.0;
#pragma unroll
    for (int c = 0; c < CH; c++) s += (double)We[d * HC + h * CH + c] * (double)ae[h * CH + c];
    v[l * (NH * E_DIM) + h * E_DIM + d] = (float)s;
}

// ---------------------------------------------------------------------------
// fp32 GEMM: C[M,256] = A[M,K] @ B[K,256].  64x64 tile, BK=32, 4x4/thread.
// Arithmetic statements verbatim from the round-2 passing kernel (FROZEN).
// R8: register prefetch. R9: float4 staging. R12: two-stage prefetch — next
// tile's global loads are issued BEFORE the current tile's regs->LDS writes
// (separate nxt registers; cur=nxt after the FMA block). Load-path only.
__global__ __launch_bounds__(256) void k_gemm(const float* __restrict__ A,
                                              const float* __restrict__ B,
                                              float* __restrict__ C, int M, int K) {
    __shared__ __align__(16) float sa[32][68];   // transposed A tile [k][row]
    __shared__ __align__(16) float sb[32][64];   // B tile [k][col]
    int row0 = blockIdx.y * 64, col0 = blockIdx.x * 64;
    int t = threadIdx.x;
    int tr = t >> 4, tc = t & 15;
    int r4 = tr * 4, c4 = tc * 4;
    float acc[4][4] = {};
    float4 cura[2], curb[2], nxta[2], nxtb[2];
    // A mapping: idx = i*256+t in [0,512): row r=idx>>3 (0..63), kc=idx&7 -> kk=kc*4..kc*4+3
    // B mapping: idx = i*256+t in [0,512): kk=idx>>4 (0..31), cc=(idx&15)*4
    // prologue: stage tile k0=0 into registers
#pragma unroll
    for (int i = 0; i < 2; i++) {
        int idx = i * 256 + t;
        int r = idx >> 3, kc = idx & 7;
        int gr = row0 + r;
        cura[i] = (gr < M) ? *(const float4*)(A + (size_t)gr * K + kc * 4)
                           : make_float4(0.f, 0.f, 0.f, 0.f);
    }
#pragma unroll
    for (int i = 0; i < 2; i++) {
        int idx = i * 256 + t;
        int kk = idx >> 4, cc = (idx & 15) * 4;
        curb[i] = *(const float4*)(B + (size_t)kk * HC + col0 + cc);
    }
    for (int k0 = 0; k0 < K; k0 += 32) {
        int kn = k0 + 32;
        if (kn < K) {                          // issue next tile's loads FIRST
#pragma unroll
            for (int i = 0; i < 2; i++) {
                int idx = i * 256 + t;
                int r = idx >> 3, kc = idx & 7;
                int gr = row0 + r;
                nxta[i] = (gr < M) ? *(const float4*)(A + (size_t)gr * K + kn + kc * 4)
                                   : make_float4(0.f, 0.f, 0.f, 0.f);
            }
#pragma unroll
            for (int i = 0; i < 2; i++) {
                int idx = i * 256 + t;
                int kk = idx >> 4, cc = (idx & 15) * 4;
                nxtb[i] = *(const float4*)(B + (size_t)(kn + kk) * HC + col0 + cc);
            }
        }
#pragma unroll
        for (int i = 0; i < 2; i++) {          // cur regs -> LDS (identical cells)
            int idx = i * 256 + t;
            int r = idx >> 3, kc = idx & 7;
            sa[kc * 4 + 0][r] = cura[i].x;
            sa[kc * 4 + 1][r] = cura[i].y;
            sa[kc * 4 + 2][r] = cura[i].z;
            sa[kc * 4 + 3][r] = cura[i].w;
        }
#pragma unroll
        for (int i = 0; i < 2; i++) {
            int idx = i * 256 + t;
            int kk = idx >> 4, cc = (idx & 15) * 4;
            *(float4*)&sb[kk][cc] = curb[i];
        }
        __syncthreads();
#pragma unroll
        for (int kk = 0; kk < 32; kk++) {      // FROZEN arithmetic statements
            float a0 = sa[kk][r4], a1 = sa[kk][r4 + 1], a2 = sa[kk][r4 + 2], a3 = sa[kk][r4 + 3];
            float b0 = sb[kk][c4], b1 = sb[kk][c4 + 1], b2 = sb[kk][c4 + 2], b3 = sb[kk][c4 + 3];
            acc[0][0] += a0 * b0; acc[0][1] += a0 * b1; acc[0][2] += a0 * b2; acc[0][3] += a0 * b3;
            acc[1][0] += a1 * b0; acc[1][1] += a1 * b1; acc[1][2] += a1 * b2; acc[1][3] += a1 * b3;
            acc[2][0] += a2 * b0; acc[2][1] += a2 * b1; acc[2][2] += a2 * b2; acc[2][3] += a2 * b3;
            acc[3][0] += a3 * b0; acc[3][1] += a3 * b1; acc[3][2] += a3 * b2; acc[3][3] += a3 * b3;
        }
        __syncthreads();
#pragma unroll
        for (int i = 0; i < 2; i++) { cura[i] = nxta[i]; curb[i] = nxtb[i]; }
    }
#pragma unroll
    for (int i = 0; i < 4; i++) {
        int gr = row0 + r4 + i;
        if (gr < M) {
            float4 o = make_float4(acc[i][0], acc[i][1], acc[i][2], acc[i][3]);
            *(float4*)&C[(size_t)gr * HC + col0 + c4] = o;
        }
    }
}

// per-node attention logits: al_s[n,h], al_d[n,h] (one block/node, wave=head)
__global__ __launch_bounds__(256) void k_al(const float* __restrict__ h,
                                            const float* __restrict__ a_s,
                                            const float* __restrict__ a_d,
                                            float* __restrict__ al_s, float* __restrict__ al_d) {
    int n = blockIdx.x;
    int t = threadIdx.x;
    int hd = t >> 6, lane = t & 63;
    double v = (double)h[(size_t)n * HC + t];
    double s1 = v * (double)a_s[t];
    double s2 = v * (double)a_d[t];
#pragma unroll
    for (int off = 32; off; off >>= 1) {
        s1 += __shfl_xor(s1, off);
        s2 += __shfl_xor(s2, off);
    }
    if (lane == 0) { al_s[n * NH + hd] = (float)s1; al_d[n * NH + hd] = (float)s2; }
}

// per-edge (incl. self-loop rows at idx>=E) edge-attr logits al_e[idx,h]
__global__ void k_ale(const float* __restrict__ ea, const float* __restrict__ mean_ea,
                      const float* __restrict__ vl, float* __restrict__ al_e) {
    int i = blockIdx.x * blockDim.x + threadIdx.x;
    if (i >= N_EDGES + N_NODES) return;
    const float* row = (i < N_EDGES) ? ea + (size_t)i * E_DIM
                                     : mean_ea + (size_t)(i - N_EDGES) * E_DIM;
    float r[E_DIM];
#pragma unroll
    for (int j = 0; j < 4; j++) {
        float4 f = ((const float4*)row)[j];
        r[j * 4 + 0] = f.x; r[j * 4 + 1] = f.y; r[j * 4 + 2] = f.z; r[j * 4 + 3] = f.w;
    }
#pragma unroll
    for (int h = 0; h < NH; h++) {
        double s = 0.0;
#pragma unroll
        for (int d = 0; d < E_DIM; d++) s += (double)r[d] * (double)vl[h * E_DIM + d];
        al_e[(size_t)i * NH + h] = (float)s;
    }
}

// per-(node,head) softmax: f64 max + f64 exp weights + f64 den, operation
// order EXACTLY as round-2's k_aggr passes A/B (edges ascending, self last).
__global__ void k_wden(const float* __restrict__ al_s, const float* __restrict__ al_d,
                       const float* __restrict__ al_e,
                       const int* __restrict__ row_start, const int* __restrict__ csr_eid,
                       const int* __restrict__ csr_src,
                       double* __restrict__ w_csr, double* __restrict__ wself,
                       double* __restrict__ den_arr) {
    int id = blockIdx.x * blockDim.x + threadIdx.x;
    if (id >= N_NODES * NH) return;
    int n = id >> 2, hd = id & 3;
    double ad_n = (double)al_d[n * NH + hd];
    double a_self = (double)al_s[n * NH + hd] + ad_n + (double)al_e[(size_t)(N_EDGES + n) * NH + hd];
    a_self = (a_self > 0.0) ? a_self : 0.2 * a_self;
    int rs = row_start[n], re = row_start[n + 1];
    // pass A: exact max (self init, edges ascending)
    double m = a_self;
    for (int i = rs; i < re; i++) {
        double a = (double)al_s[csr_src[i] * NH + hd] + ad_n
                 + (double)al_e[(size_t)csr_eid[i] * NH + hd];
        a = (a > 0.0) ? a : 0.2 * a;
        if (a > m) m = a;
    }
    // pass B: f64 exp weights, den ascending then self LAST
    double den = 0.0;
    for (int i = rs; i < re; i++) {
        double a = (double)al_s[csr_src[i] * NH + hd] + ad_n
                 + (double)al_e[(size_t)csr_eid[i] * NH + hd];
        a = (a > 0.0) ? a : 0.2 * a;
        double w = exp(a - m);
        den += w;
        w_csr[(size_t)i * NH + hd] = w;
    }
    double ws = exp(a_self - m);
    den += ws;
    wself[n * NH + hd] = ws;
    den_arr[n * NH + hd] = den;
}

// GAT aggregation: pure gather-FMA. block per dest node, wave=head, lane=channel.
// f64 adds in ascending edge order, self-loop term last (bit-order == round 2).
// R12: 8->4->1 load cascade (same statement form, same add order);
// x_out store skipped on the last layer (dead).
__global__ __launch_bounds__(256) void k_aggr(const float* __restrict__ hbuf,
                                              const double* __restrict__ w_csr,
                                              const double* __restrict__ wself,
                                              const double* __restrict__ den_arr,
                                              const int* __restrict__ row_start,
                                              const int* __restrict__ csr_src,
                                              const float* __restrict__ bias,
                                              float* __restrict__ x_out,
                                              float* __restrict__ add,
                                              int layer0, int write_x) {
    int n = blockIdx.x;
    int t = threadIdx.x;
    int hd = t >> 6;
    int rs = row_start[n], re = row_start[n + 1];
    double acc = 0.0;
    int i = rs;
    for (; i + 7 < re; i += 8) {
        int s0 = csr_src[i],     s1 = csr_src[i + 1], s2 = csr_src[i + 2], s3 = csr_src[i + 3];
        int s4 = csr_src[i + 4], s5 = csr_src[i + 5], s6 = csr_src[i + 6], s7 = csr_src[i + 7];
        double w0 = w_csr[(size_t)i * NH + hd];
        double w1 = w_csr[(size_t)(i + 1) * NH + hd];
        double w2 = w_csr[(size_t)(i + 2) * NH + hd];
        double w3 = w_csr[(size_t)(i + 3) * NH + hd];
        double w4 = w_csr[(size_t)(i + 4) * NH + hd];
        double w5 = w_csr[(size_t)(i + 5) * NH + hd];
        double w6 = w_csr[(size_t)(i + 6) * NH + hd];
        double w7 = w_csr[(size_t)(i + 7) * NH + hd];
        float h0 = hbuf[(size_t)s0 * HC + t];
        float h1 = hbuf[(size_t)s1 * HC + t];
        float h2 = hbuf[(size_t)s2 * HC + t];
        float h3 = hbuf[(size_t)s3 * HC + t];
        float h4 = hbuf[(size_t)s4 * HC + t];
        float h5 = hbuf[(size_t)s5 * HC + t];
        float h6 = hbuf[(size_t)s6 * HC + t];
        float h7 = hbuf[(size_t)s7 * HC + t];
        acc += w0 * (double)h0;        // sequential f64 adds: order preserved
        acc += w1 * (double)h1;
        acc += w2 * (double)h2;
        acc += w3 * (double)h3;
        acc += w4 * (double)h4;
        acc += w5 * (double)h5;
        acc += w6 * (double)h6;
        acc += w7 * (double)h7;
    }
    for (; i + 3 < re; i += 4) {
        int s0 = csr_src[i], s1 = csr_src[i + 1], s2 = csr_src[i + 2], s3 = csr_src[i + 3];
        double w0 = w_csr[(size_t)i * NH + hd];
        double w1 = w_csr[(size_t)(i + 1) * NH + hd];
        double w2 = w_csr[(size_t)(i + 2) * NH + hd];
        double w3 = w_csr[(size_t)(i + 3) * NH + hd];
        float h0 = hbuf[(size_t)s0 * HC + t];
        float h1 = hbuf[(size_t)s1 * HC + t];
        float h2 = hbuf[(size_t)s2 * HC + t];
        float h3 = hbuf[(size_t)s3 * HC + t];
        acc += w0 * (double)h0;
        acc += w1 * (double)h1;
        acc += w2 * (double)h2;
        acc += w3 * (double)h3;
    }
    for (; i < re; i++)
        acc += w_csr[(size_t)i * NH + hd] * (double)hbuf[(size_t)csr_src[i] * HC + t];
    acc += wself[n * NH + hd] * (double)hbuf[(size_t)n * HC + t];   // self last
    double den = den_arr[n * NH + hd];
    float val = (float)(acc / (den + 1e-16)) + bias[t];
    val = (val > 0.f) ? val : 0.f;       // relu
    if (write_x) x_out[(size_t)n * HC + t] = val;
    if (layer0) add[(size_t)n * HC + t] = val;
    else        add[(size_t)n * HC + t] += val;
}

// per-node scalars p = add·w_rel, q = add·w_root  (f64, wave per node)
__global__ __launch_bounds__(256) void k_pq(const float* __restrict__ add,
                                            const float* __restrict__ w_rel,
                                            const float* __restrict__ w_root,
                                            double* __restrict__ p, double* __restrict__ q) {
    int w = blockIdx.x * 4 + (threadIdx.x >> 6);
    int lane = threadIdx.x & 63;
    if (w >= N_NODES) return;
    const float* row = add + (size_t)w * HC;
    double s1 = 0.0, s2 = 0.0;
#pragma unroll
    for (int j = 0; j < 4; j++) {
        double v = (double)row[lane + j * 64];
        s1 += v * (double)w_rel[lane + j * 64];
        s2 += v * (double)w_root[lane + j * 64];
    }
#pragma unroll
    for (int off = 32; off; off >>= 1) {
        s1 += __shfl_xor(s1, off);
        s2 += __shfl_xor(s2, off);
    }
    if (lane == 0) { p[w] = s1; q[w] = s2; }
}

// score[n] = b_rel + q[n] + sum_{e in(n), ascending} p[src[e]]  (f64, stored f32)
__global__ void k_score(const double* __restrict__ p, const double* __restrict__ q,
                        const float* __restrict__ b_rel,
                        const int* __restrict__ row_start, const int* __restrict__ csr_src,
                        float* __restrict__ score) {
    int n = blockIdx.x * blockDim.x + threadIdx.x;
    if (n >= N_NODES) return;
    double s = (double)b_rel[0] + q[n];
    int rs = row_start[n], re = row_start[n + 1];
    for (int i = rs; i < re; i++) s += p[csr_src[i]];
    score[n] = (float)s;
}

// batch is SORTED -> per-graph bounds via binary search (no atomics).
__global__ void k_gbounds(const int* __restrict__ batch, int* __restrict__ gstart,
                          int* __restrict__ gcount) {
    int g = threadIdx.x;
    if (g >= NG) return;
    int lo = 0, hi = N_NODES;
    while (lo < hi) { int mid = (lo + hi) >> 1; if (batch[mid] < g) lo = mid + 1; else hi = mid; }
    int a = lo;
    lo = a; hi = N_NODES;
    while (lo < hi) { int mid = (lo + hi) >> 1; if (batch[mid] < g + 1) lo = mid + 1; else hi = mid; }
    gstart[g] = a;
    gcount[g] = lo - a;
}

// stable per-graph descending rank (== jnp.lexsort((-score, batch)))
__global__ void k_rank(const float* __restrict__ score, const int* __restrict__ batch,
                       const int* __restrict__ gstart, const int* __restrict__ gcount,
                       int* __restrict__ outrow) {
    int n = blockIdx.x * blockDim.x + threadIdx.x;
    if (n >= N_NODES) return;
    int g = batch[n];
    int s0 = gstart[g], cnt = gcount[g];
    float my = score[n];
    int r = 0;
    for (int j = s0; j < s0 + cnt; j++) {
        float sj = score[j];
        r += (sj > my) || (sj == my && j < n);
    }
    outrow[n] = s0 + r;
}

// final: out[rank(n)] = sigmoid(tanh(score[n]) * (add[n] @ wl) + bl)  (wave per node)
__global__ __launch_bounds__(256) void k_out(const float* __restrict__ add,
                                             const float* __restrict__ score,
                                             const int* __restrict__ outrow,
                                             const float* __restrict__ wl,
                                             const float* __restrict__ bl,
                                             float* __restrict__ out) {
    int w = blockIdx.x * 4 + (threadIdx.x >> 6);
    int lane = threadIdx.x & 63;
    if (w >= N_NODES) return;
    float tsc = tanhf(score[w]);
    const float* row = add + (size_t)w * HC;
    float acc[NOUT] = {};
#pragma unroll
    for (int j = 0; j < 4; j++) {
        float a = row[lane + j * 64];
        const float* wlr = wl + (size_t)(lane + j * 64) * NOUT;
#pragma unroll
        for (int o = 0; o < NOUT; o++) acc[o] += a * wlr[o];
    }
#pragma unroll
    for (int o = 0; o < NOUT; o++)
#pragma unroll
        for (int off = 32; off; off >>= 1) acc[o] += __shfl_xor(acc[o], off);
    if (lane == 0) {
        int r = outrow[w];
        float* orow = out + (size_t)r * NOUT;
#pragma unroll
        for (int o = 0; o < NOUT; o++) {
            float z = tsc * acc[o] + bl[o];
            orow[o] = 1.f / (1.f + expf(-z));
        }
    }
}

// ---------------------------------------------------------------------------
extern "C" void kernel_launch(void* const* d_in, const int* in_sizes, int n_in,
                              void* d_out, int out_size, void* d_ws, size_t ws_size,
                              hipStream_t stream) {
    const float* x     = (const float*)d_in[0];
    const int*   ei    = (const int*)d_in[1];
    const int*   src   = ei;
    const int*   dst   = ei + N_EDGES;
    const int*   batch = (const int*)d_in[2];
    const float* ea    = (const float*)d_in[3];
    const float* W[3]  = {(const float*)d_in[4],  (const float*)d_in[10], (const float*)d_in[16]};
    const float* As[3] = {(const float*)d_in[5],  (const float*)d_in[11], (const float*)d_in[17]};
    const float* Ad[3] = {(const float*)d_in[6],  (const float*)d_in[12], (const float*)d_in[18]};
    const float* We[3] = {(const float*)d_in[7],  (const float*)d_in[13], (const float*)d_in[19]};
    const float* Ae[3] = {(const float*)d_in[8],  (const float*)d_in[14], (const float*)d_in[20]};
    const float* Bs[3] = {(const float*)d_in[9],  (const float*)d_in[15], (const float*)d_in[21]};
    const float* w_rel  = (const float*)d_in[22];
    const float* b_rel  = (const float*)d_in[23];
    const float* w_root = (const float*)d_in[24];
    const float* wl     = (const float*)d_in[25];
    const float* bl     = (const float*)d_in[26];
    float* out = (float*)d_out;

    // workspace carve-up (256B aligned)
    char* wp = (char*)d_ws;
    auto alloc = [&](size_t bytes) { char* p = wp; wp += (bytes + 255) & ~(size_t)255; return p; };
    float* h_buf   = (float*)alloc((size_t)N_NODES * HC * 4);
    float* x_cur   = (float*)alloc((size_t)N_NODES * HC * 4);
    float* add     = (float*)alloc((size_t)N_NODES * HC * 4);
    float* mean_ea = (float*)alloc((size_t)N_NODES * E_DIM * 4);
    float* al_s    = (float*)alloc((size_t)N_NODES * NH * 4);
    float* al_d    = (float*)alloc((size_t)N_NODES * NH * 4);
    float* al_e    = (float*)alloc((size_t)(N_EDGES + N_NODES) * NH * 4);
    double* w_csr  = (double*)alloc((size_t)N_EDGES * NH * 8);
    double* wself  = (double*)alloc((size_t)N_NODES * NH * 8);
    double* den    = (double*)alloc((size_t)N_NODES * NH * 8);
    double* p_buf  = (double*)alloc((size_t)N_NODES * 8);
    double* q_buf  = (double*)alloc((size_t)N_NODES * 8);
    float* score   = (float*)alloc((size_t)N_NODES * 4);
    float* v_buf   = (float*)alloc(3 * NH * E_DIM * 4);
    int* deg       = (int*)alloc((size_t)N_NODES * 4);
    int* row_start = (int*)alloc((size_t)(N_NODES + 1) * 4);
    int* fill      = (int*)alloc((size_t)N_NODES * 4);
    int* csr_eid   = (int*)alloc((size_t)N_EDGES * 4);
    int* csr_src   = (int*)alloc((size_t)N_EDGES * 4);
    int* bsum      = (int*)alloc(64 * 4);
    int* gcount    = (int*)alloc(NG * 4);
    int* gstart    = (int*)alloc(NG * 4);
    int* outrow    = (int*)alloc((size_t)N_NODES * 4);
    if ((size_t)(wp - (char*)d_ws) > ws_size) return;  // insufficient ws -> fail loudly

    // zero the atomically-accumulated buffers (ws is poisoned 0xAA each call)
    hipMemsetAsync(deg, 0, (size_t)N_NODES * 4, stream);
    hipMemsetAsync(fill, 0, (size_t)N_NODES * 4, stream);

    const int TB = 256;
    int gE = (N_EDGES + TB - 1) / TB;
    int gN = (N_NODES + TB - 1) / TB;
    int nScanBlocks = (N_NODES + 1023) / 1024;

    k_deg<<<gE, TB, 0, stream>>>(dst, deg);
    k_scan1<<<nScanBlocks, 1024, 0, stream>>>(deg, row_start, bsum);
    k_scan2<<<1, 64, 0, stream>>>(bsum, nScanBlocks);
    k_scan3<<<gN, TB, 0, stream>>>(row_start, bsum);
    k_scatter<<<gE, TB, 0, stream>>>(dst, row_start, fill, csr_eid);
    k_sortrows<<<gN, TB, 0, stream>>>(row_start, csr_eid);
    k_gather_src<<<gE, TB, 0, stream>>>(csr_eid, src, csr_src);
    k_mean_csr<<<gN, TB, 0, stream>>>(ea, row_start, csr_eid, mean_ea);
    k_v<<<1, 192, 0, stream>>>(We[0], Ae[0], We[1], Ae[1], We[2], Ae[2], v_buf);

    for (int l = 0; l < 3; l++) {
        const float* xin = (l == 0) ? x : x_cur;
        int K = (l == 0) ? F_IN : HC;
        dim3 ggrid(HC / 64, (N_NODES + 63) / 64);
        k_gemm<<<ggrid, TB, 0, stream>>>(xin, W[l], h_buf, N_NODES, K);
        k_al<<<N_NODES, TB, 0, stream>>>(h_buf, As[l], Ad[l], al_s, al_d);
        k_ale<<<(N_EDGES + N_NODES + TB - 1) / TB, TB, 0, stream>>>(
            ea, mean_ea, v_buf + l * NH * E_DIM, al_e);
        k_wden<<<(N_NODES * NH + TB - 1) / TB, TB, 0, stream>>>(
            al_s, al_d, al_e, row_start, csr_eid, csr_src, w_csr, wself, den);
        k_aggr<<<N_NODES, TB, 0, stream>>>(h_buf, w_csr, wself, den, row_start, csr_src,
                                           Bs[l], x_cur, add, (l == 0) ? 1 : 0,
                                           (l < 2) ? 1 : 0);
    }

    k_pq<<<(N_NODES + 3) / 4, TB, 0, stream>>>(add, w_rel, w_root, p_buf, q_buf);
    k_score<<<gN, TB, 0, stream>>>(p_buf, q_buf, b_rel, row_start, csr_src, score);
    k_gbounds<<<1, 64, 0, stream>>>(batch, gstart, gcount);
    k_rank<<<gN, TB, 0, stream>>>(score, batch, gstart, gcount, outrow);
    k_out<<<(N_NODES + 3) / 4, TB, 0, stream>>>(add, score, outrow, wl, bl, out);
}

// Round 13
// 1211.609 us; speedup vs baseline: 1.0577x; 1.0577x over previous
//
#include <hip/hip_runtime.h>
#include <hip/hip_bf16.h>
#include <math.h>

// Problem constants (from reference)
constexpr int N_NODES = 50000;
constexpr int N_EDGES = 400000;
constexpr int F_IN    = 128;
constexpr int E_DIM   = 16;
constexpr int NH      = 4;    // heads
constexpr int CH      = 64;   // channels/head
constexpr int HC      = 256;  // NH*CH
constexpr int NG      = 64;   // graphs
constexpr int NOUT    = 10;

// NOTE ON NUMERICS: the final per-graph sort is bit-sensitive (one marginal
// score pair flips at ~1e-7 perturbations of `add`). The f64 chain below is
// the exact chain of the round-2 PASSING run. EMPIRICAL RULES:
//  - (R3, R6, R10 failures) any restructure that changes the FROZEN GEMM FMA
//    block's statements OR causes the compiler to clone/specialize it flips
//    output bits.
//  - (R7, R8, R9, R11 passes) load/store-path changes OUTSIDE the frozen
//    block (alignment, padding, load widths, register prefetch, staging
//    remaps, load batching preserving f64 add order, dead-store elimination)
//    are bit-safe.
//  - (R12 regression) holding two prefetch register sets across the FMA
//    block spills to scratch (WRITE_SIZE 78->238 MB) — keep exactly ONE
//    in-flight staging set (the R9/R11 structure).

// ---------------------------------------------------------------------------
// integer in-degree per destination
__global__ void k_deg(const int* __restrict__ dst, int* __restrict__ deg) {
    int e = blockIdx.x * blockDim.x + threadIdx.x;
    if (e >= N_EDGES) return;
    atomicAdd(&deg[dst[e]], 1);
}

// 3-phase exclusive scan of deg -> row_start (integer-exact)
__global__ void k_scan1(const int* __restrict__ deg, int* __restrict__ row_start,
                        int* __restrict__ bsum) {
    __shared__ int sh[1024];
    int i = blockIdx.x * 1024 + threadIdx.x;
    int v = (i < N_NODES) ? deg[i] : 0;
    sh[threadIdx.x] = v;
    __syncthreads();
    for (int off = 1; off < 1024; off <<= 1) {
        int t = (threadIdx.x >= off) ? sh[threadIdx.x - off] : 0;
        __syncthreads();
        sh[threadIdx.x] += t;
        __syncthreads();
    }
    if (i < N_NODES) row_start[i + 1] = sh[threadIdx.x];   // local inclusive
    if (threadIdx.x == 1023) bsum[blockIdx.x] = sh[1023];
}
__global__ void k_scan2(int* __restrict__ bsum, int nb) {
    if (threadIdx.x == 0) {
        int s = 0;
        for (int b = 0; b < nb; b++) { int t = bsum[b]; bsum[b] = s; s += t; }
    }
}
__global__ void k_scan3(int* __restrict__ row_start, const int* __restrict__ bsum) {
    int i = blockIdx.x * blockDim.x + threadIdx.x;
    if (i == 0) row_start[0] = 0;
    if (i < N_NODES) row_start[i + 1] += bsum[i >> 10];
}

// counting-sort scatter of edge ids into CSR (by dst); racy fill order,
// k_sortrows restores deterministic ascending edge order afterwards.
__global__ void k_scatter(const int* __restrict__ dst, const int* __restrict__ row_start,
                          int* __restrict__ fill, int* __restrict__ csr_eid) {
    int e = blockIdx.x * blockDim.x + threadIdx.x;
    if (e >= N_EDGES) return;
    int d = dst[e];
    int pos = row_start[d] + atomicAdd(&fill[d], 1);
    csr_eid[pos] = e;
}

// insertion-sort each CSR row ascending (deg ~ Poisson(8))
__global__ void k_sortrows(const int* __restrict__ row_start, int* __restrict__ csr_eid) {
    int n = blockIdx.x * blockDim.x + threadIdx.x;
    if (n >= N_NODES) return;
    int rs = row_start[n], re = row_start[n + 1];
    for (int i = rs + 1; i < re; i++) {
        int key = csr_eid[i];
        int j = i - 1;
        while (j >= rs && csr_eid[j] > key) { csr_eid[j + 1] = csr_eid[j]; j--; }
        csr_eid[j + 1] = key;
    }
}

// pre-gather source node ids at (sorted) CSR positions
__global__ void k_gather_src(const int* __restrict__ csr_eid, const int* __restrict__ src,
                             int* __restrict__ csr_src) {
    int i = blockIdx.x * blockDim.x + threadIdx.x;
    if (i >= N_EDGES) return;
    csr_src[i] = src[csr_eid[i]];
}

// deterministic mean edge_attr per destination (ascending edge order, f64)
__global__ void k_mean_csr(const float* __restrict__ ea, const int* __restrict__ row_start,
                           const int* __restrict__ csr_eid, float* __restrict__ mean_ea) {
    int n = blockIdx.x * blockDim.x + threadIdx.x;
    if (n >= N_NODES) return;
    int rs = row_start[n], re = row_start[n + 1];
    double acc[E_DIM];
#pragma unroll
    for (int d = 0; d < E_DIM; d++) acc[d] = 0.0;
    for (int i = rs; i < re; i++) {
        const float* row = ea + (size_t)csr_eid[i] * E_DIM;
#pragma unroll
        for (int d = 0; d < E_DIM; d++) acc[d] += (double)row[d];
    }
    double dg = (double)(re - rs);
    if (dg < 1.0) dg = 1.0;
    float* orow = mean_ea + (size_t)n * E_DIM;
#pragma unroll
    for (int d = 0; d < E_DIM; d++) orow[d] = (float)(acc[d] / dg);
}

// v[l][h][d] = sum_c We_l[d][h*64+c] * ae_l[h][c]  (edge-logit projection, 3 layers)
__global__ void k_v(const float* __restrict__ we1, const float* __restrict__ ae1,
                    const float* __restrict__ we2, const float* __restrict__ ae2,
                    const float* __restrict__ we3, const float* __restrict__ ae3,
                    float* __restrict__ v) {
    int t = threadIdx.x;            // 0..191
    if (t >= 3 * NH * E_DIM) return;
    int l = t / (NH * E_DIM);
    int rem = t % (NH * E_DIM);
    int h = rem / E_DIM, d = rem % E_DIM;
    const float* We = (l == 0) ? we1 : (l == 1) ? we2 : we3;
    const float* ae = (l == 0) ? ae1 : (l == 1) ? ae2 : ae3;
    double s = 0.0;
#pragma unroll
    for (int c = 0; c < CH; c++) s += (double)We[d * HC + h * CH + c] * (double)ae[h * CH + c];
    v[l * (NH * E_DIM) + h * E_DIM + d] = (float)s;
}

// ---------------------------------------------------------------------------
// fp32 GEMM: C[M,256] = A[M,K] @ B[K,256].  64x64 tile, BK=32, 4x4/thread.
// Arithmetic statements verbatim from the round-2 passing kernel (FROZEN).
// R8: register double-buffer on staging (bit-safe).
// R9: staging loads vectorized to float4 (bit-safe).
// R12's two-stage prefetch REVERTED (scratch spill, see header note).
__global__ __launch_bounds__(256) void k_gemm(const float* __restrict__ A,
                                              const float* __restrict__ B,
                                              float* __restrict__ C, int M, int K) {
    __shared__ __align__(16) float sa[32][68];   // transposed A tile [k][row]
    __shared__ __align__(16) float sb[32][64];   // B tile [k][col]
    int row0 = blockIdx.y * 64, col0 = blockIdx.x * 64;
    int t = threadIdx.x;
    int tr = t >> 4, tc = t & 15;
    int r4 = tr * 4, c4 = tc * 4;
    float acc[4][4] = {};
    float4 areg[2], breg[2];
    // A mapping: idx = i*256+t in [0,512): row r=idx>>3 (0..63), kc=idx&7 -> kk=kc*4..kc*4+3
    // B mapping: idx = i*256+t in [0,512): kk=idx>>4 (0..31), cc=(idx&15)*4
    // prologue: stage tile k0=0 into registers
#pragma unroll
    for (int i = 0; i < 2; i++) {
        int idx = i * 256 + t;
        int r = idx >> 3, kc = idx & 7;
        int gr = row0 + r;
        areg[i] = (gr < M) ? *(const float4*)(A + (size_t)gr * K + kc * 4)
                           : make_float4(0.f, 0.f, 0.f, 0.f);
    }
#pragma unroll
    for (int i = 0; i < 2; i++) {
        int idx = i * 256 + t;
        int kk = idx >> 4, cc = (idx & 15) * 4;
        breg[i] = *(const float4*)(B + (size_t)kk * HC + col0 + cc);
    }
    for (int k0 = 0; k0 < K; k0 += 32) {
#pragma unroll
        for (int i = 0; i < 2; i++) {          // regs -> LDS (identical values/cells)
            int idx = i * 256 + t;
            int r = idx >> 3, kc = idx & 7;
            sa[kc * 4 + 0][r] = areg[i].x;
            sa[kc * 4 + 1][r] = areg[i].y;
            sa[kc * 4 + 2][r] = areg[i].z;
            sa[kc * 4 + 3][r] = areg[i].w;
        }
#pragma unroll
        for (int i = 0; i < 2; i++) {
            int idx = i * 256 + t;
            int kk = idx >> 4, cc = (idx & 15) * 4;
            *(float4*)&sb[kk][cc] = breg[i];
        }
        __syncthreads();
        int kn = k0 + 32;
        if (kn < K) {                          // prefetch next tile (latency hidden)
#pragma unroll
            for (int i = 0; i < 2; i++) {
                int idx = i * 256 + t;
                int r = idx >> 3, kc = idx & 7;
                int gr = row0 + r;
                areg[i] = (gr < M) ? *(const float4*)(A + (size_t)gr * K + kn + kc * 4)
                                   : make_float4(0.f, 0.f, 0.f, 0.f);
            }
#pragma unroll
            for (int i = 0; i < 2; i++) {
                int idx = i * 256 + t;
                int kk = idx >> 4, cc = (idx & 15) * 4;
                breg[i] = *(const float4*)(B + (size_t)(kn + kk) * HC + col0 + cc);
            }
        }
#pragma unroll
        for (int kk = 0; kk < 32; kk++) {      // FROZEN arithmetic statements
            float a0 = sa[kk][r4], a1 = sa[kk][r4 + 1], a2 = sa[kk][r4 + 2], a3 = sa[kk][r4 + 3];
            float b0 = sb[kk][c4], b1 = sb[kk][c4 + 1], b2 = sb[kk][c4 + 2], b3 = sb[kk][c4 + 3];
            acc[0][0] += a0 * b0; acc[0][1] += a0 * b1; acc[0][2] += a0 * b2; acc[0][3] += a0 * b3;
            acc[1][0] += a1 * b0; acc[1][1] += a1 * b1; acc[1][2] += a1 * b2; acc[1][3] += a1 * b3;
            acc[2][0] += a2 * b0; acc[2][1] += a2 * b1; acc[2][2] += a2 * b2; acc[2][3] += a2 * b3;
            acc[3][0] += a3 * b0; acc[3][1] += a3 * b1; acc[3][2] += a3 * b2; acc[3][3] += a3 * b3;
        }
        __syncthreads();
    }
#pragma unroll
    for (int i = 0; i < 4; i++) {
        int gr = row0 + r4 + i;
        if (gr < M) {
            float4 o = make_float4(acc[i][0], acc[i][1], acc[i][2], acc[i][3]);
            *(float4*)&C[(size_t)gr * HC + col0 + c4] = o;
        }
    }
}

// per-node attention logits: al_s[n,h], al_d[n,h] (one block/node, wave=head)
__global__ __launch_bounds__(256) void k_al(const float* __restrict__ h,
                                            const float* __restrict__ a_s,
                                            const float* __restrict__ a_d,
                                            float* __restrict__ al_s, float* __restrict__ al_d) {
    int n = blockIdx.x;
    int t = threadIdx.x;
    int hd = t >> 6, lane = t & 63;
    double v = (double)h[(size_t)n * HC + t];
    double s1 = v * (double)a_s[t];
    double s2 = v * (double)a_d[t];
#pragma unroll
    for (int off = 32; off; off >>= 1) {
        s1 += __shfl_xor(s1, off);
        s2 += __shfl_xor(s2, off);
    }
    if (lane == 0) { al_s[n * NH + hd] = (float)s1; al_d[n * NH + hd] = (float)s2; }
}

// per-edge (incl. self-loop rows at idx>=E) edge-attr logits al_e[idx,h]
__global__ void k_ale(const float* __restrict__ ea, const float* __restrict__ mean_ea,
                      const float* __restrict__ vl, float* __restrict__ al_e) {
    int i = blockIdx.x * blockDim.x + threadIdx.x;
    if (i >= N_EDGES + N_NODES) return;
    const float* row = (i < N_EDGES) ? ea + (size_t)i * E_DIM
                                     : mean_ea + (size_t)(i - N_EDGES) * E_DIM;
    float r[E_DIM];
#pragma unroll
    for (int j = 0; j < 4; j++) {
        float4 f = ((const float4*)row)[j];
        r[j * 4 + 0] = f.x; r[j * 4 + 1] = f.y; r[j * 4 + 2] = f.z; r[j * 4 + 3] = f.w;
    }
#pragma unroll
    for (int h = 0; h < NH; h++) {
        double s = 0.0;
#pragma unroll
        for (int d = 0; d < E_DIM; d++) s += (double)r[d] * (double)vl[h * E_DIM + d];
        al_e[(size_t)i * NH + h] = (float)s;
    }
}

// per-(node,head) softmax: f64 max + f64 exp weights + f64 den, operation
// order EXACTLY as round-2's k_aggr passes A/B (edges ascending, self last).
__global__ void k_wden(const float* __restrict__ al_s, const float* __restrict__ al_d,
                       const float* __restrict__ al_e,
                       const int* __restrict__ row_start, const int* __restrict__ csr_eid,
                       const int* __restrict__ csr_src,
                       double* __restrict__ w_csr, double* __restrict__ wself,
                       double* __restrict__ den_arr) {
    int id = blockIdx.x * blockDim.x + threadIdx.x;
    if (id >= N_NODES * NH) return;
    int n = id >> 2, hd = id & 3;
    double ad_n = (double)al_d[n * NH + hd];
    double a_self = (double)al_s[n * NH + hd] + ad_n + (double)al_e[(size_t)(N_EDGES + n) * NH + hd];
    a_self = (a_self > 0.0) ? a_self : 0.2 * a_self;
    int rs = row_start[n], re = row_start[n + 1];
    // pass A: exact max (self init, edges ascending)
    double m = a_self;
    for (int i = rs; i < re; i++) {
        double a = (double)al_s[csr_src[i] * NH + hd] + ad_n
                 + (double)al_e[(size_t)csr_eid[i] * NH + hd];
        a = (a > 0.0) ? a : 0.2 * a;
        if (a > m) m = a;
    }
    // pass B: f64 exp weights, den ascending then self LAST
    double den = 0.0;
    for (int i = rs; i < re; i++) {
        double a = (double)al_s[csr_src[i] * NH + hd] + ad_n
                 + (double)al_e[(size_t)csr_eid[i] * NH + hd];
        a = (a > 0.0) ? a : 0.2 * a;
        double w = exp(a - m);
        den += w;
        w_csr[(size_t)i * NH + hd] = w;
    }
    double ws = exp(a_self - m);
    den += ws;
    wself[n * NH + hd] = ws;
    den_arr[n * NH + hd] = den;
}

// GAT aggregation: pure gather-FMA. block per dest node, wave=head, lane=channel.
// f64 adds in ascending edge order, self-loop term last (bit-order == round 2).
// R12 (kept): 8->4->1 load cascade (same statement form, same add order);
// x_out store skipped on the last layer (dead).
__global__ __launch_bounds__(256) void k_aggr(const float* __restrict__ hbuf,
                                              const double* __restrict__ w_csr,
                                              const double* __restrict__ wself,
                                              const double* __restrict__ den_arr,
                                              const int* __restrict__ row_start,
                                              const int* __restrict__ csr_src,
                                              const float* __restrict__ bias,
                                              float* __restrict__ x_out,
                                              float* __restrict__ add,
                                              int layer0, int write_x) {
    int n = blockIdx.x;
    int t = threadIdx.x;
    int hd = t >> 6;
    int rs = row_start[n], re = row_start[n + 1];
    double acc = 0.0;
    int i = rs;
    for (; i + 7 < re; i += 8) {
        int s0 = csr_src[i],     s1 = csr_src[i + 1], s2 = csr_src[i + 2], s3 = csr_src[i + 3];
        int s4 = csr_src[i + 4], s5 = csr_src[i + 5], s6 = csr_src[i + 6], s7 = csr_src[i + 7];
        double w0 = w_csr[(size_t)i * NH + hd];
        double w1 = w_csr[(size_t)(i + 1) * NH + hd];
        double w2 = w_csr[(size_t)(i + 2) * NH + hd];
        double w3 = w_csr[(size_t)(i + 3) * NH + hd];
        double w4 = w_csr[(size_t)(i + 4) * NH + hd];
        double w5 = w_csr[(size_t)(i + 5) * NH + hd];
        double w6 = w_csr[(size_t)(i + 6) * NH + hd];
        double w7 = w_csr[(size_t)(i + 7) * NH + hd];
        float h0 = hbuf[(size_t)s0 * HC + t];
        float h1 = hbuf[(size_t)s1 * HC + t];
        float h2 = hbuf[(size_t)s2 * HC + t];
        float h3 = hbuf[(size_t)s3 * HC + t];
        float h4 = hbuf[(size_t)s4 * HC + t];
        float h5 = hbuf[(size_t)s5 * HC + t];
        float h6 = hbuf[(size_t)s6 * HC + t];
        float h7 = hbuf[(size_t)s7 * HC + t];
        acc += w0 * (double)h0;        // sequential f64 adds: order preserved
        acc += w1 * (double)h1;
        acc += w2 * (double)h2;
        acc += w3 * (double)h3;
        acc += w4 * (double)h4;
        acc += w5 * (double)h5;
        acc += w6 * (double)h6;
        acc += w7 * (double)h7;
    }
    for (; i + 3 < re; i += 4) {
        int s0 = csr_src[i], s1 = csr_src[i + 1], s2 = csr_src[i + 2], s3 = csr_src[i + 3];
        double w0 = w_csr[(size_t)i * NH + hd];
        double w1 = w_csr[(size_t)(i + 1) * NH + hd];
        double w2 = w_csr[(size_t)(i + 2) * NH + hd];
        double w3 = w_csr[(size_t)(i + 3) * NH + hd];
        float h0 = hbuf[(size_t)s0 * HC + t];
        float h1 = hbuf[(size_t)s1 * HC + t];
        float h2 = hbuf[(size_t)s2 * HC + t];
        float h3 = hbuf[(size_t)s3 * HC + t];
        acc += w0 * (double)h0;
        acc += w1 * (double)h1;
        acc += w2 * (double)h2;
        acc += w3 * (double)h3;
    }
    for (; i < re; i++)
        acc += w_csr[(size_t)i * NH + hd] * (double)hbuf[(size_t)csr_src[i] * HC + t];
    acc += wself[n * NH + hd] * (double)hbuf[(size_t)n * HC + t];   // self last
    double den = den_arr[n * NH + hd];
    float val = (float)(acc / (den + 1e-16)) + bias[t];
    val = (val > 0.f) ? val : 0.f;       // relu
    if (write_x) x_out[(size_t)n * HC + t] = val;
    if (layer0) add[(size_t)n * HC + t] = val;
    else        add[(size_t)n * HC + t] += val;
}

// per-node scalars p = add·w_rel, q = add·w_root  (f64, wave per node)
__global__ __launch_bounds__(256) void k_pq(const float* __restrict__ add,
                                            const float* __restrict__ w_rel,
                                            const float* __restrict__ w_root,
                                            double* __restrict__ p, double* __restrict__ q) {
    int w = blockIdx.x * 4 + (threadIdx.x >> 6);
    int lane = threadIdx.x & 63;
    if (w >= N_NODES) return;
    const float* row = add + (size_t)w * HC;
    double s1 = 0.0, s2 = 0.0;
#pragma unroll
    for (int j = 0; j < 4; j++) {
        double v = (double)row[lane + j * 64];
        s1 += v * (double)w_rel[lane + j * 64];
        s2 += v * (double)w_root[lane + j * 64];
    }
#pragma unroll
    for (int off = 32; off; off >>= 1) {
        s1 += __shfl_xor(s1, off);
        s2 += __shfl_xor(s2, off);
    }
    if (lane == 0) { p[w] = s1; q[w] = s2; }
}

// score[n] = b_rel + q[n] + sum_{e in(n), ascending} p[src[e]]  (f64, stored f32)
__global__ void k_score(const double* __restrict__ p, const double* __restrict__ q,
                        const float* __restrict__ b_rel,
                        const int* __restrict__ row_start, const int* __restrict__ csr_src,
                        float* __restrict__ score) {
    int n = blockIdx.x * blockDim.x + threadIdx.x;
    if (n >= N_NODES) return;
    double s = (double)b_rel[0] + q[n];
    int rs = row_start[n], re = row_start[n + 1];
    for (int i = rs; i < re; i++) s += p[csr_src[i]];
    score[n] = (float)s;
}

// batch is SORTED -> per-graph bounds via binary search (no atomics).
__global__ void k_gbounds(const int* __restrict__ batch, int* __restrict__ gstart,
                          int* __restrict__ gcount) {
    int g = threadIdx.x;
    if (g >= NG) return;
    int lo = 0, hi = N_NODES;
    while (lo < hi) { int mid = (lo + hi) >> 1; if (batch[mid] < g) lo = mid + 1; else hi = mid; }
    int a = lo;
    lo = a; hi = N_NODES;
    while (lo < hi) { int mid = (lo + hi) >> 1; if (batch[mid] < g + 1) lo = mid + 1; else hi = mid; }
    gstart[g] = a;
    gcount[g] = lo - a;
}

// stable per-graph descending rank (== jnp.lexsort((-score, batch)))
__global__ void k_rank(const float* __restrict__ score, const int* __restrict__ batch,
                       const int* __restrict__ gstart, const int* __restrict__ gcount,
                       int* __restrict__ outrow) {
    int n = blockIdx.x * blockDim.x + threadIdx.x;
    if (n >= N_NODES) return;
    int g = batch[n];
    int s0 = gstart[g], cnt = gcount[g];
    float my = score[n];
    int r = 0;
    for (int j = s0; j < s0 + cnt; j++) {
        float sj = score[j];
        r += (sj > my) || (sj == my && j < n);
    }
    outrow[n] = s0 + r;
}

// final: out[rank(n)] = sigmoid(tanh(score[n]) * (add[n] @ wl) + bl)  (wave per node)
__global__ __launch_bounds__(256) void k_out(const float* __restrict__ add,
                                             const float* __restrict__ score,
                                             const int* __restrict__ outrow,
                                             const float* __restrict__ wl,
                                             const float* __restrict__ bl,
                                             float* __restrict__ out) {
    int w = blockIdx.x * 4 + (threadIdx.x >> 6);
    int lane = threadIdx.x & 63;
    if (w >= N_NODES) return;
    float tsc = tanhf(score[w]);
    const float* row = add + (size_t)w * HC;
    float acc[NOUT] = {};
#pragma unroll
    for (int j = 0; j < 4; j++) {
        float a = row[lane + j * 64];
        const float* wlr = wl + (size_t)(lane + j * 64) * NOUT;
#pragma unroll
        for (int o = 0; o < NOUT; o++) acc[o] += a * wlr[o];
    }
#pragma unroll
    for (int o = 0; o < NOUT; o++)
#pragma unroll
        for (int off = 32; off; off >>= 1) acc[o] += __shfl_xor(acc[o], off);
    if (lane == 0) {
        int r = outrow[w];
        float* orow = out + (size_t)r * NOUT;
#pragma unroll
        for (int o = 0; o < NOUT; o++) {
            float z = tsc * acc[o] + bl[o];
            orow[o] = 1.f / (1.f + expf(-z));
        }
    }
}

// ---------------------------------------------------------------------------
extern "C" void kernel_launch(void* const* d_in, const int* in_sizes, int n_in,
                              void* d_out, int out_size, void* d_ws, size_t ws_size,
                              hipStream_t stream) {
    const float* x     = (const float*)d_in[0];
    const int*   ei    = (const int*)d_in[1];
    const int*   src   = ei;
    const int*   dst   = ei + N_EDGES;
    const int*   batch = (const int*)d_in[2];
    const float* ea    = (const float*)d_in[3];
    const float* W[3]  = {(const float*)d_in[4],  (const float*)d_in[10], (const float*)d_in[16]};
    const float* As[3] = {(const float*)d_in[5],  (const float*)d_in[11], (const float*)d_in[17]};
    const float* Ad[3] = {(const float*)d_in[6],  (const float*)d_in[12], (const float*)d_in[18]};
    const float* We[3] = {(const float*)d_in[7],  (const float*)d_in[13], (const float*)d_in[19]};
    const float* Ae[3] = {(const float*)d_in[8],  (const float*)d_in[14], (const float*)d_in[20]};
    const float* Bs[3] = {(const float*)d_in[9],  (const float*)d_in[15], (const float*)d_in[21]};
    const float* w_rel  = (const float*)d_in[22];
    const float* b_rel  = (const float*)d_in[23];
    const float* w_root = (const float*)d_in[24];
    const float* wl     = (const float*)d_in[25];
    const float* bl     = (const float*)d_in[26];
    float* out = (float*)d_out;

    // workspace carve-up (256B aligned)
    char* wp = (char*)d_ws;
    auto alloc = [&](size_t bytes) { char* p = wp; wp += (bytes + 255) & ~(size_t)255; return p; };
    float* h_buf   = (float*)alloc((size_t)N_NODES * HC * 4);
    float* x_cur   = (float*)alloc((size_t)N_NODES * HC * 4);
    float* add     = (float*)alloc((size_t)N_NODES * HC * 4);
    float* mean_ea = (float*)alloc((size_t)N_NODES * E_DIM * 4);
    float* al_s    = (float*)alloc((size_t)N_NODES * NH * 4);
    float* al_d    = (float*)alloc((size_t)N_NODES * NH * 4);
    float* al_e    = (float*)alloc((size_t)(N_EDGES + N_NODES) * NH * 4);
    double* w_csr  = (double*)alloc((size_t)N_EDGES * NH * 8);
    double* wself  = (double*)alloc((size_t)N_NODES * NH * 8);
    double* den    = (double*)alloc((size_t)N_NODES * NH * 8);
    double* p_buf  = (double*)alloc((size_t)N_NODES * 8);
    double* q_buf  = (double*)alloc((size_t)N_NODES * 8);
    float* score   = (float*)alloc((size_t)N_NODES * 4);
    float* v_buf   = (float*)alloc(3 * NH * E_DIM * 4);
    int* deg       = (int*)alloc((size_t)N_NODES * 4);
    int* row_start = (int*)alloc((size_t)(N_NODES + 1) * 4);
    int* fill      = (int*)alloc((size_t)N_NODES * 4);
    int* csr_eid   = (int*)alloc((size_t)N_EDGES * 4);
    int* csr_src   = (int*)alloc((size_t)N_EDGES * 4);
    int* bsum      = (int*)alloc(64 * 4);
    int* gcount    = (int*)alloc(NG * 4);
    int* gstart    = (int*)alloc(NG * 4);
    int* outrow    = (int*)alloc((size_t)N_NODES * 4);
    if ((size_t)(wp - (char*)d_ws) > ws_size) return;  // insufficient ws -> fail loudly

    // zero the atomically-accumulated buffers (ws is poisoned 0xAA each call)
    hipMemsetAsync(deg, 0, (size_t)N_NODES * 4, stream);
    hipMemsetAsync(fill, 0, (size_t)N_NODES * 4, stream);

    const int TB = 256;
    int gE = (N_EDGES + TB - 1) / TB;
    int gN = (N_NODES + TB - 1) / TB;
    int nScanBlocks = (N_NODES + 1023) / 1024;

    k_deg<<<gE, TB, 0, stream>>>(dst, deg);
    k_scan1<<<nScanBlocks, 1024, 0, stream>>>(deg, row_start, bsum);
    k_scan2<<<1, 64, 0, stream>>>(bsum, nScanBlocks);
    k_scan3<<<gN, TB, 0, stream>>>(row_start, bsum);
    k_scatter<<<gE, TB, 0, stream>>>(dst, row_start, fill, csr_eid);
    k_sortrows<<<gN, TB, 0, stream>>>(row_start, csr_eid);
    k_gather_src<<<gE, TB, 0, stream>>>(csr_eid, src, csr_src);
    k_mean_csr<<<gN, TB, 0, stream>>>(ea, row_start, csr_eid, mean_ea);
    k_v<<<1, 192, 0, stream>>>(We[0], Ae[0], We[1], Ae[1], We[2], Ae[2], v_buf);

    for (int l = 0; l < 3; l++) {
        const float* xin = (l == 0) ? x : x_cur;
        int K = (l == 0) ? F_IN : HC;
        dim3 ggrid(HC / 64, (N_NODES + 63) / 64);
        k_gemm<<<ggrid, TB, 0, stream>>>(xin, W[l], h_buf, N_NODES, K);
        k_al<<<N_NODES, TB, 0, stream>>>(h_buf, As[l], Ad[l], al_s, al_d);
        k_ale<<<(N_EDGES + N_NODES + TB - 1) / TB, TB, 0, stream>>>(
            ea, mean_ea, v_buf + l * NH * E_DIM, al_e);
        k_wden<<<(N_NODES * NH + TB - 1) / TB, TB, 0, stream>>>(
            al_s, al_d, al_e, row_start, csr_eid, csr_src, w_csr, wself, den);
        k_aggr<<<N_NODES, TB, 0, stream>>>(h_buf, w_csr, wself, den, row_start, csr_src,
                                           Bs[l], x_cur, add, (l == 0) ? 1 : 0,
                                           (l < 2) ? 1 : 0);
    }

    k_pq<<<(N_NODES + 3) / 4, TB, 0, stream>>>(add, w_rel, w_root, p_buf, q_buf);
    k_score<<<gN, TB, 0, stream>>>(p_buf, q_buf, b_rel, row_start, csr_src, score);
    k_gbounds<<<1, 64, 0, stream>>>(batch, gstart, gcount);
    k_rank<<<gN, TB, 0, stream>>>(score, batch, gstart, gcount, outrow);
    k_out<<<(N_NODES + 3) / 4, TB, 0, stream>>>(add, score, outrow, wl, bl, out);
}